// Round 11
// baseline (108.456 us; speedup 1.0000x reference)
//
#include <hip/hip_runtime.h>
#include <hip/hip_bf16.h>
#include <math.h>

#define B_  1024
#define S_  50
#define E_  512
#define L_  1024
#define D_  10
#define NN  1023   // N_NODES
#define LN_EPS 1e-5f
#define CBLK 72    // compose tile blocks (9 x 8 of 64x64 over 513x512)

typedef short short8 __attribute__((ext_vector_type(8)));
typedef float f32x4  __attribute__((ext_vector_type(4)));
typedef unsigned short u16;
typedef unsigned int   u32;

union PackU { unsigned int u[4]; short8 s; };

// Split 8 f32 into bf16 hi (truncation; lo captures remainder exactly) and lo (RNE).
__device__ inline void split8(const float r[8], short8& hi, short8& lo) {
    PackU H, L;
#pragma unroll
    for (int q = 0; q < 4; ++q) {
        const unsigned int u0 = __float_as_uint(r[2*q+0]);
        const unsigned int u1 = __float_as_uint(r[2*q+1]);
        H.u[q] = (u0 >> 16) | (u1 & 0xFFFF0000u);
        const float h0 = __uint_as_float(u0 & 0xFFFF0000u);
        const float h1 = __uint_as_float(u1 & 0xFFFF0000u);
        const float l0 = r[2*q+0] - h0;
        const float l1 = r[2*q+1] - h1;
        unsigned int p;
        asm("v_cvt_pk_bf16_f32 %0, %1, %2" : "=v"(p) : "v"(l0), "v"(l1));
        L.u[q] = p;
    }
    hi = H.s; lo = L.s;
}

__device__ inline void split1(float v, u16& h, u16& l) {
    const unsigned int u = __float_as_uint(v);
    h = (u16)(u >> 16);
    const float hf = __uint_as_float(u & 0xFFFF0000u);
    const float lo = v - hf;
    unsigned int p;
    asm("v_cvt_pk_bf16_f32 %0, %1, %2" : "=v"(p) : "v"(lo), "v"(lo));
    l = (u16)(p & 0xFFFFu);
}

__device__ inline void split2(float v0, float v1, u32& hw, u32& lw) {
    const unsigned int u0 = __float_as_uint(v0);
    const unsigned int u1 = __float_as_uint(v1);
    hw = (u0 >> 16) | (u1 & 0xFFFF0000u);
    const float h0 = __uint_as_float(u0 & 0xFFFF0000u);
    const float h1 = __uint_as_float(u1 & 0xFFFF0000u);
    const float l0 = v0 - h0;
    const float l1 = v1 - h1;
    asm("v_cvt_pk_bf16_f32 %0, %1, %2" : "=v"(lw) : "v"(l0), "v"(l1));
}

// ---------------- bf16-plane pipelined 64x64 GEMM core (CHUNKS k-steps of 32) -------
struct BFrag { short8 ah[2], al[2], bh[2], bl[2]; };

__device__ inline void loadB(BFrag& f,
                             const u16* pah0, const u16* pal0,
                             const u16* pah1, const u16* pal1,
                             const u16* pbh0, const u16* pbl0,
                             const u16* pbh1, const u16* pbl1, int off) {
    f.ah[0] = *reinterpret_cast<const short8*>(pah0 + off);
    f.al[0] = *reinterpret_cast<const short8*>(pal0 + off);
    f.ah[1] = *reinterpret_cast<const short8*>(pah1 + off);
    f.al[1] = *reinterpret_cast<const short8*>(pal1 + off);
    f.bh[0] = *reinterpret_cast<const short8*>(pbh0 + off);
    f.bl[0] = *reinterpret_cast<const short8*>(pbl0 + off);
    f.bh[1] = *reinterpret_cast<const short8*>(pbh1 + off);
    f.bl[1] = *reinterpret_cast<const short8*>(pbl1 + off);
}

template<int TERMS>
__device__ inline void compB(const BFrag& f, f32x4 acc[2][2]) {
#pragma unroll
    for (int i = 0; i < 2; ++i)
#pragma unroll
        for (int j = 0; j < 2; ++j) {
            acc[i][j] = __builtin_amdgcn_mfma_f32_16x16x32_bf16(f.ah[i], f.bh[j], acc[i][j], 0, 0, 0);
            acc[i][j] = __builtin_amdgcn_mfma_f32_16x16x32_bf16(f.ah[i], f.bl[j], acc[i][j], 0, 0, 0);
            acc[i][j] = __builtin_amdgcn_mfma_f32_16x16x32_bf16(f.al[i], f.bh[j], acc[i][j], 0, 0, 0);
            if (TERMS == 4)
                acc[i][j] = __builtin_amdgcn_mfma_f32_16x16x32_bf16(f.al[i], f.bl[j], acc[i][j], 0, 0, 0);
        }
}

template<int TERMS, int CHUNKS>
__device__ inline void gemmB(const u16* pah0, const u16* pal0,
                             const u16* pah1, const u16* pal1,
                             const u16* pbh0, const u16* pbl0,
                             const u16* pbh1, const u16* pbl1,
                             f32x4 acc[2][2]) {
    BFrag f0, f1;
    loadB(f0, pah0, pal0, pah1, pal1, pbh0, pbl0, pbh1, pbl1, 0);
#pragma unroll 1
    for (int kt = 0; kt < CHUNKS; kt += 2) {
        loadB(f1, pah0, pal0, pah1, pal1, pbh0, pbl0, pbh1, pbl1, (kt + 1) * 32);
        compB<TERMS>(f0, acc);
        if (kt + 2 < CHUNKS) loadB(f0, pah0, pal0, pah1, pal1, pbh0, pbl0, pbh1, pbl1, (kt + 2) * 32);
        compB<TERMS>(f1, acc);
    }
}

// ---------------- f32-pair-A pipelined 64x64 GEMM core (split-K consumer) -----------
struct FPFrag { float aA[2][8], aB[2][8]; short8 bh[2], bl[2]; };

__device__ inline void loadFP(FPFrag& f,
                              const float* pa0A, const float* pa0B,
                              const float* pa1A, const float* pa1B,
                              const u16* pbh0, const u16* pbl0,
                              const u16* pbh1, const u16* pbl1, int off) {
    *reinterpret_cast<float4*>(&f.aA[0][0]) = *reinterpret_cast<const float4*>(pa0A + off);
    *reinterpret_cast<float4*>(&f.aA[0][4]) = *reinterpret_cast<const float4*>(pa0A + off + 4);
    *reinterpret_cast<float4*>(&f.aB[0][0]) = *reinterpret_cast<const float4*>(pa0B + off);
    *reinterpret_cast<float4*>(&f.aB[0][4]) = *reinterpret_cast<const float4*>(pa0B + off + 4);
    *reinterpret_cast<float4*>(&f.aA[1][0]) = *reinterpret_cast<const float4*>(pa1A + off);
    *reinterpret_cast<float4*>(&f.aA[1][4]) = *reinterpret_cast<const float4*>(pa1A + off + 4);
    *reinterpret_cast<float4*>(&f.aB[1][0]) = *reinterpret_cast<const float4*>(pa1B + off);
    *reinterpret_cast<float4*>(&f.aB[1][4]) = *reinterpret_cast<const float4*>(pa1B + off + 4);
    f.bh[0] = *reinterpret_cast<const short8*>(pbh0 + off);
    f.bl[0] = *reinterpret_cast<const short8*>(pbl0 + off);
    f.bh[1] = *reinterpret_cast<const short8*>(pbh1 + off);
    f.bl[1] = *reinterpret_cast<const short8*>(pbl1 + off);
}

__device__ inline void compFP(const FPFrag& f, f32x4 acc[2][2]) {
    short8 ah[2], al[2];
#pragma unroll
    for (int i = 0; i < 2; ++i) {
        float rr[8];
#pragma unroll
        for (int q = 0; q < 8; ++q) rr[q] = f.aA[i][q] + f.aB[i][q];
        split8(rr, ah[i], al[i]);
    }
#pragma unroll
    for (int i = 0; i < 2; ++i)
#pragma unroll
        for (int j = 0; j < 2; ++j) {
            acc[i][j] = __builtin_amdgcn_mfma_f32_16x16x32_bf16(ah[i], f.bh[j], acc[i][j], 0, 0, 0);
            acc[i][j] = __builtin_amdgcn_mfma_f32_16x16x32_bf16(ah[i], f.bl[j], acc[i][j], 0, 0, 0);
            acc[i][j] = __builtin_amdgcn_mfma_f32_16x16x32_bf16(al[i], f.bh[j], acc[i][j], 0, 0, 0);
        }
}

template<int CHUNKS>
__device__ inline void gemmFP(const float* pa0A, const float* pa0B,
                              const float* pa1A, const float* pa1B,
                              const u16* pbh0, const u16* pbl0,
                              const u16* pbh1, const u16* pbl1,
                              f32x4 acc[2][2]) {
    FPFrag f0, f1;
    loadFP(f0, pa0A, pa0B, pa1A, pa1B, pbh0, pbl0, pbh1, pbl1, 0);
#pragma unroll 1
    for (int kt = 0; kt < CHUNKS; kt += 2) {
        loadFP(f1, pa0A, pa0B, pa1A, pa1B, pbh0, pbl0, pbh1, pbl1, (kt + 1) * 32);
        compFP(f0, acc);
        if (kt + 2 < CHUNKS) loadFP(f0, pa0A, pa0B, pa1A, pa1B, pbh0, pbl0, pbh1, pbl1, (kt + 2) * 32);
        compFP(f1, acc);
    }
}

// ---------------- embed row: one block = one batch row, writes bf16 planes ---------
__device__ inline void do_embed_row(const int* __restrict__ ids,
                                    const float* __restrict__ emb,
                                    u16* __restrict__ xah, u16* __restrict__ xal, int b) {
    const int t = threadIdx.x;
    float a0 = 0.f, a1 = 0.f;
    const int* idr = ids + b * S_;
#pragma unroll 5
    for (int s = 0; s < S_; ++s) {
        const float2 v = *reinterpret_cast<const float2*>(emb + (long)idr[s] * E_ + 2 * t);
        a0 += v.x;
        a1 += v.y;
    }
    a0 *= (1.f / S_);
    a1 *= (1.f / S_);

    __shared__ float red[256];
    red[t] = a0 + a1;
    __syncthreads();
    for (int off = 128; off > 0; off >>= 1) {
        if (t < off) red[t] += red[t + off];
        __syncthreads();
    }
    const float mean = red[0] * (1.f / E_);
    __syncthreads();
    const float d0 = a0 - mean, d1 = a1 - mean;
    red[t] = d0 * d0 + d1 * d1;
    __syncthreads();
    for (int off = 128; off > 0; off >>= 1) {
        if (t < off) red[t] += red[t + off];
        __syncthreads();
    }
    const float var = red[0] * (1.f / E_);
    const float inv = 1.f / sqrtf(var + LN_EPS);
    u32 hw, lw;
    split2(d0 * inv, d1 * inv, hw, lw);
    *reinterpret_cast<u32*>(xah + (long)b * E_ + 2 * t) = hw;
    *reinterpret_cast<u32*>(xal + (long)b * E_ + 2 * t) = lw;
}

// ---------------- Dpack: D planes + gvec = thb[:,1]-thb[:,0] ------------------------
__device__ inline void do_dpack(const float* __restrict__ thW,
                                u16* __restrict__ Dh, u16* __restrict__ Dl,
                                const float* __restrict__ thb,
                                float* __restrict__ gvec, int part) {
    const int tid = threadIdx.x;
    const int p0 = part * 256 + tid;
    if (p0 < NN)       gvec[p0] = thb[2 * p0 + 1] - thb[2 * p0];
    else if (p0 == NN) gvec[p0] = 0.f;
    const int total = NN * 256;
    const int nth = 64 * 256;
    for (int p = p0; p < total; p += nth) {
        const int n = p >> 8;
        const int kp = p & 255;
        const float4 v = *reinterpret_cast<const float4*>(thW + (long)n * 1024 + kp * 4);
        u32 hw, lw;
        split2(v.y - v.x, v.w - v.z, hw, lw);
        *reinterpret_cast<u32*>(Dh + (long)n * E_ + kp * 2) = hw;
        *reinterpret_cast<u32*>(Dl + (long)n * E_ + kp * 2) = lw;
    }
}

// ---------------- shared compose epilogue: planes + transposed planes + cvec --------
__device__ inline void compose_epilogue(f32x4 acc[2][2], int row_base, int col_base,
                                        int kg, int r_lo,
                                        const float* __restrict__ Bbias,
                                        u16* __restrict__ Ch, u16* __restrict__ Cl,
                                        u16* __restrict__ Th, u16* __restrict__ Tl,
                                        float* __restrict__ cvec) {
#pragma unroll
    for (int j = 0; j < 2; ++j) {
        const int col = col_base + j * 16 + r_lo;
        const float bb = Bbias[col];
#pragma unroll
        for (int i = 0; i < 2; ++i) {
            const int row0 = row_base + i * 16 + kg * 4;
            union { ushort4 v; u16 e[4]; } th, tl;
#pragma unroll
            for (int r2 = 0; r2 < 4; ++r2) {
                const int row = row0 + r2;
                float v = acc[i][j][r2];
                if (row == E_) { v += bb; cvec[col] = v; }
                u16 h, l;
                split1(v, h, l);
                if (row <= E_ && Ch != nullptr) {
                    Ch[(long)row * E_ + col] = h;
                    Cl[(long)row * E_ + col] = l;
                }
                th.e[r2] = h; tl.e[r2] = l;
            }
            if (row0 + 3 < E_) {
                *reinterpret_cast<ushort4*>(Th + (long)col * E_ + row0) = th.v;
                *reinterpret_cast<ushort4*>(Tl + (long)col * E_ + row0) = tl.v;
            }
        }
    }
}

// ---------------- compose0: P2 = [Wh;bh] ∘ [Wh;bh]  (f32 inputs, 4-term) ------------
__device__ inline void do_compose0(const float* __restrict__ Wh, const float* __restrict__ bh,
                                   u16* __restrict__ Ch, u16* __restrict__ Cl,
                                   u16* __restrict__ Th, u16* __restrict__ Tl,
                                   float* __restrict__ cvec, int bid) {
    const int tid  = threadIdx.x;
    const int wid  = tid >> 6;
    const int lane = tid & 63;
    const int r_lo = lane & 15;
    const int kg   = lane >> 4;
    const int row_base = (bid >> 3) * 64 + (wid >> 1) * 32;
    const int col_base = (bid & 7) * 64 + (wid & 1) * 32;
    f32x4 acc[2][2] = {};
#pragma unroll 2
    for (int kt = 0; kt < E_; kt += 32) {
        const int ks = kt + kg * 8;
        short8 ah[2], al[2], bhf[2], blf[2];
#pragma unroll
        for (int i = 0; i < 2; ++i) {
            const int row = row_base + i * 16 + r_lo;
            const float* ap = (row < E_) ? (Wh + (long)row * E_ + ks) : (bh + ks);
            const float4 v0 = *reinterpret_cast<const float4*>(ap);
            const float4 v1 = *reinterpret_cast<const float4*>(ap + 4);
            const float rr[8] = {v0.x, v0.y, v0.z, v0.w, v1.x, v1.y, v1.z, v1.w};
            split8(rr, ah[i], al[i]);
        }
#pragma unroll
        for (int j = 0; j < 2; ++j) {
            const int c = col_base + j * 16 + r_lo;
            float rr[8];
#pragma unroll
            for (int q = 0; q < 8; ++q) rr[q] = Wh[(long)(ks + q) * E_ + c];
            split8(rr, bhf[j], blf[j]);
        }
#pragma unroll
        for (int i = 0; i < 2; ++i)
#pragma unroll
            for (int j = 0; j < 2; ++j) {
                acc[i][j] = __builtin_amdgcn_mfma_f32_16x16x32_bf16(ah[i], bhf[j], acc[i][j], 0, 0, 0);
                acc[i][j] = __builtin_amdgcn_mfma_f32_16x16x32_bf16(ah[i], blf[j], acc[i][j], 0, 0, 0);
                acc[i][j] = __builtin_amdgcn_mfma_f32_16x16x32_bf16(al[i], bhf[j], acc[i][j], 0, 0, 0);
                acc[i][j] = __builtin_amdgcn_mfma_f32_16x16x32_bf16(al[i], blf[j], acc[i][j], 0, 0, 0);
            }
    }
    compose_epilogue(acc, row_base, col_base, kg, r_lo, bh, Ch, Cl, Th, Tl, cvec);
}

// ---------------- compose (bf16 planes): C = A(513x512) ∘then B ---------------------
__device__ inline void do_composeB(const u16* __restrict__ Ah, const u16* __restrict__ Al,
                                   const u16* __restrict__ Bh, const u16* __restrict__ Bl,
                                   const float* __restrict__ Bbias,
                                   u16* __restrict__ Ch, u16* __restrict__ Cl,
                                   u16* __restrict__ Th, u16* __restrict__ Tl,
                                   float* __restrict__ cvec, int bid) {
    const int tid  = threadIdx.x;
    const int wid  = tid >> 6;
    const int lane = tid & 63;
    const int r_lo = lane & 15;
    const int kg   = lane >> 4;
    const int row_base = (bid >> 3) * 64 + (wid >> 1) * 32;
    const int col_base = (bid & 7) * 64 + (wid & 1) * 32;

    int ra0 = row_base + r_lo;        if (ra0 > E_) ra0 = E_;
    int ra1 = row_base + 16 + r_lo;   if (ra1 > E_) ra1 = E_;
    const long rb0 = col_base + r_lo;
    const long rb1 = col_base + 16 + r_lo;

    f32x4 acc[2][2] = {};
    gemmB<4, 16>(Ah + (long)ra0 * E_ + kg * 8, Al + (long)ra0 * E_ + kg * 8,
                 Ah + (long)ra1 * E_ + kg * 8, Al + (long)ra1 * E_ + kg * 8,
                 Bh + rb0 * E_ + kg * 8,       Bl + rb0 * E_ + kg * 8,
                 Bh + rb1 * E_ + kg * 8,       Bl + rb1 * E_ + kg * 8, acc);

    compose_epilogue(acc, row_base, col_base, kg, r_lo, Bbias, Ch, Cl, Th, Tl, cvec);
}

// ---------------- fused kernels -----------------------------------------------------
// k0: P2 compose + ALL embed rows + Dpack(+gvec)
__global__ __launch_bounds__(256) void k_fused0(const float* __restrict__ Wh,
                                                const float* __restrict__ bh,
                                                u16* __restrict__ Ch0, u16* __restrict__ Cl0,
                                                u16* __restrict__ Th0, u16* __restrict__ Tl0,
                                                float* __restrict__ cvec0,
                                                const int* __restrict__ ids,
                                                const float* __restrict__ emb,
                                                u16* __restrict__ xah, u16* __restrict__ xal,
                                                const float* __restrict__ thW,
                                                u16* __restrict__ Dh, u16* __restrict__ Dl,
                                                const float* __restrict__ thb,
                                                float* __restrict__ gvec) {
    const int bid = blockIdx.x;
    if (bid < CBLK)             do_compose0(Wh, bh, Ch0, Cl0, Th0, Tl0, cvec0, bid);
    else if (bid < CBLK + 1024) do_embed_row(ids, emb, xah, xal, bid - CBLK);
    else                        do_dpack(thW, Dh, Dl, thb, gvec, bid - CBLK - 1024);
}

// k1: P4 compose (T planes only) + y1 = xa@M2 + c2 as split-K partial pair
__global__ __launch_bounds__(256) void k_fused1(const u16* __restrict__ Ch0, const u16* __restrict__ Cl0,
                                                const u16* __restrict__ Th0, const u16* __restrict__ Tl0,
                                                const float* __restrict__ cvec0,
                                                u16* __restrict__ Th1, u16* __restrict__ Tl1,
                                                float* __restrict__ cvec1,
                                                const u16* __restrict__ xah, const u16* __restrict__ xal,
                                                float* __restrict__ y1A, float* __restrict__ y1B) {
    const int bid = blockIdx.x;
    if (bid < CBLK) {
        do_composeB(Ch0, Cl0, Th0, Tl0, cvec0, nullptr, nullptr, Th1, Tl1, cvec1, bid);  // P4
        return;
    }
    const int t    = bid - CBLK;        // 0..255
    const int kk   = t >> 7;            // K-half
    const int tile = t & 127;
    const int koff = kk * 256;
    const int tid  = threadIdx.x;
    const int wid  = tid >> 6;
    const int lane = tid & 63;
    const int r_lo = lane & 15;
    const int kg   = lane >> 4;
    const int row_base = (tile >> 3) * 64 + (wid >> 1) * 32;
    const int col_base = (tile & 7) * 64 + (wid & 1) * 32;
    const long ra0 = row_base + r_lo;
    const long ra1 = row_base + 16 + r_lo;
    const long rb0 = col_base + r_lo;
    const long rb1 = col_base + 16 + r_lo;

    f32x4 acc[2][2] = {};
    gemmB<3, 8>(xah + ra0 * E_ + koff + kg * 8, xal + ra0 * E_ + koff + kg * 8,
                xah + ra1 * E_ + koff + kg * 8, xal + ra1 * E_ + koff + kg * 8,
                Th0 + rb0 * E_ + koff + kg * 8, Tl0 + rb0 * E_ + koff + kg * 8,
                Th0 + rb1 * E_ + koff + kg * 8, Tl0 + rb1 * E_ + koff + kg * 8, acc);

    float* Y = kk ? y1B : y1A;
#pragma unroll
    for (int j = 0; j < 2; ++j) {
        const int col = col_base + j * 16 + r_lo;
        const float bb = kk ? cvec0[col] : 0.f;
#pragma unroll
        for (int i = 0; i < 2; ++i)
#pragma unroll
            for (int r2 = 0; r2 < 4; ++r2) {
                const int row = row_base + i * 16 + kg * 4 + r2;
                Y[(long)row * E_ + col] = acc[i][j][r2] + bb;
            }
    }
}

// k2/k3: Y(pair) = X(pair) @ M4 + c4, split-K, f32 in / f32 out
__global__ __launch_bounds__(256) void k_applyFP(const float* __restrict__ XA, const float* __restrict__ XB,
                                                 const u16* __restrict__ Mh, const u16* __restrict__ Ml,
                                                 const float* __restrict__ cvec,
                                                 float* __restrict__ YA, float* __restrict__ YB) {
    const int bid  = blockIdx.x;        // 0..255
    const int kk   = bid >> 7;
    const int tile = bid & 127;
    const int koff = kk * 256;
    const int tid  = threadIdx.x;
    const int wid  = tid >> 6;
    const int lane = tid & 63;
    const int r_lo = lane & 15;
    const int kg   = lane >> 4;
    const int row_base = (tile >> 3) * 64 + (wid >> 1) * 32;
    const int col_base = (tile & 7) * 64 + (wid & 1) * 32;
    const long ra0 = row_base + r_lo;
    const long ra1 = row_base + 16 + r_lo;
    const long rb0 = col_base + r_lo;
    const long rb1 = col_base + 16 + r_lo;

    f32x4 acc[2][2] = {};
    gemmFP<8>(XA + ra0 * E_ + koff + kg * 8, XB + ra0 * E_ + koff + kg * 8,
              XA + ra1 * E_ + koff + kg * 8, XB + ra1 * E_ + koff + kg * 8,
              Mh + rb0 * E_ + koff + kg * 8, Ml + rb0 * E_ + koff + kg * 8,
              Mh + rb1 * E_ + koff + kg * 8, Ml + rb1 * E_ + koff + kg * 8, acc);

    float* Y = kk ? YB : YA;
#pragma unroll
    for (int j = 0; j < 2; ++j) {
        const int col = col_base + j * 16 + r_lo;
        const float bb = kk ? cvec[col] : 0.f;
#pragma unroll
        for (int i = 0; i < 2; ++i)
#pragma unroll
            for (int r2 = 0; r2 < 4; ++r2) {
                const int row = row_base + i * 16 + kg * 4 + r2;
                Y[(long)row * E_ + col] = acc[i][j][r2] + bb;
            }
    }
}

// k4: sg(pair) = y3(pair) @ dTheta, split-K (bias+sigmoid deferred to leaf)
__global__ __launch_bounds__(256) void k_thetaFP(const float* __restrict__ XA, const float* __restrict__ XB,
                                                 const u16* __restrict__ Dh, const u16* __restrict__ Dl,
                                                 float* __restrict__ sgA, float* __restrict__ sgB) {
    const int bid  = blockIdx.x;        // 0..511
    const int kk   = bid >> 8;
    const int tile = bid & 255;
    const int koff = kk * 256;
    const int tid  = threadIdx.x;
    const int wid  = tid >> 6;
    const int lane = tid & 63;
    const int r_lo = lane & 15;
    const int kg   = lane >> 4;
    const int row_base = (tile >> 4) * 64 + (wid >> 1) * 32;
    const int col_base = (tile & 15) * 64 + (wid & 1) * 32;

    long c0 = col_base + r_lo;        if (c0 > NN - 1) c0 = NN - 1;
    long c1 = col_base + 16 + r_lo;   if (c1 > NN - 1) c1 = NN - 1;
    const long ra0 = row_base + r_lo;
    const long ra1 = row_base + 16 + r_lo;

    f32x4 acc[2][2] = {};
    gemmFP<8>(XA + ra0 * E_ + koff + kg * 8, XB + ra0 * E_ + koff + kg * 8,
              XA + ra1 * E_ + koff + kg * 8, XB + ra1 * E_ + koff + kg * 8,
              Dh + c0 * E_ + koff + kg * 8,  Dl + c0 * E_ + koff + kg * 8,
              Dh + c1 * E_ + koff + kg * 8,  Dl + c1 * E_ + koff + kg * 8, acc);

    float* S = kk ? sgB : sgA;
#pragma unroll
    for (int j = 0; j < 2; ++j) {
        const int col = col_base + j * 16 + r_lo;
#pragma unroll
        for (int i = 0; i < 2; ++i)
#pragma unroll
            for (int r2 = 0; r2 < 4; ++r2) {
                const int row = row_base + i * 16 + kg * 4 + r2;
                if (col < NN) {
                    S[(long)row * 1024 + col] = acc[i][j][r2];
                }
            }
    }
}

// k5: leaf — sum partials + gvec, sigmoid, LDS gather product
__global__ __launch_bounds__(256) void k_leaf2(const float* __restrict__ sgA,
                                               const float* __restrict__ sgB,
                                               const float* __restrict__ gvec,
                                               float* __restrict__ out) {
    __shared__ float s[1024];
    const int b = blockIdx.x;
    const int tid = threadIdx.x;
    const float4 a = reinterpret_cast<const float4*>(sgA + (long)b * 1024)[tid];
    const float4 c = reinterpret_cast<const float4*>(sgB + (long)b * 1024)[tid];
    const float4 g = reinterpret_cast<const float4*>(gvec)[tid];
    float4 r;
    r.x = 1.f / (1.f + __expf(-(a.x + c.x + g.x)));
    r.y = 1.f / (1.f + __expf(-(a.y + c.y + g.y)));
    r.z = 1.f / (1.f + __expf(-(a.z + c.z + g.z)));
    r.w = 1.f / (1.f + __expf(-(a.w + c.w + g.w)));
    reinterpret_cast<float4*>(s)[tid] = r;
    __syncthreads();
    float* orow = out + (long)b * L_;
#pragma unroll 1
    for (int q = 0; q < 4; ++q) {
        const int l = q * 256 + tid;
        float p = 1.f;
#pragma unroll
        for (int t = 0; t < D_; ++t) {
            const int node = (1 << t) - 1 + (l >> (D_ - t));
            const int bit  = (l >> (D_ - 1 - t)) & 1;
            const float sv = s[node];
            p *= bit ? sv : (1.f - sv);
        }
        orow[l] = p;
    }
}

extern "C" void kernel_launch(void* const* d_in, const int* in_sizes, int n_in,
                              void* d_out, int out_size, void* d_ws, size_t ws_size,
                              hipStream_t stream) {
    const int*   ids = (const int*)d_in[0];
    const float* emb = (const float*)d_in[1];
    const float* Wh  = (const float*)d_in[2];
    const float* bh  = (const float*)d_in[3];
    const float* thW = (const float*)d_in[4];
    const float* thb = (const float*)d_in[5];
    float* out = (float*)d_out;

    char* ws = (char*)d_ws;
    const size_t MB = 1u << 20;
    u16* xah = (u16*)(ws + 0 * MB);            // [1024][512] bf16 planes
    u16* xal = (u16*)(ws + 1 * MB);
    float* y1A = (float*)(ws + 2 * MB);        // f32 partial pairs, 2 MB each
    float* y1B = (float*)(ws + 4 * MB);
    float* y2A = (float*)(ws + 6 * MB);
    float* y2B = (float*)(ws + 8 * MB);
    float* y3A = (float*)(ws + 10 * MB);
    float* y3B = (float*)(ws + 12 * MB);
    float* sgA = (float*)(ws + 14 * MB);       // [1024][1024] f32, 4 MB each
    float* sgB = (float*)(ws + 18 * MB);
    u16* Dh  = (u16*)(ws + 22 * MB);           // [1023][512]
    u16* Dl  = (u16*)(ws + 23 * MB);
    u16* Ch0 = (u16*)(ws + 24 * MB);           // [513][512] P2 normal planes
    u16* Cl0 = (u16*)(ws + 25 * MB);
    u16* Th0 = (u16*)(ws + 26 * MB);           // [512][512] transposed planes
    u16* Tl0 = (u16*)(ws + 26 * MB + 512 * 1024);
    u16* Th1 = (u16*)(ws + 27 * MB);
    u16* Tl1 = (u16*)(ws + 27 * MB + 512 * 1024);
    float* cvec0 = (float*)(ws + 28 * MB);
    float* cvec1 = (float*)(ws + 28 * MB + 4096);
    float* gvec  = (float*)(ws + 28 * MB + 8192);

    // 1) P2 compose + ALL embed rows + Dpack(+gvec)
    k_fused0<<<CBLK + 1024 + 64, 256, 0, stream>>>(Wh, bh, Ch0, Cl0, Th0, Tl0, cvec0,
                                                   ids, emb, xah, xal, thW, Dh, Dl,
                                                   thb, gvec);

    // 2) P4 compose + y1 = xa@M2 + c2 (split-K pair)
    k_fused1<<<CBLK + 256, 256, 0, stream>>>(Ch0, Cl0, Th0, Tl0, cvec0,
                                             Th1, Tl1, cvec1,
                                             xah, xal, y1A, y1B);

    // 3) y2 = y1@M4 + c4 (split-K pair)
    k_applyFP<<<256, 256, 0, stream>>>(y1A, y1B, Th1, Tl1, cvec1, y2A, y2B);

    // 4) y3 = y2@M4 + c4   (f^10 = f^4 ∘ f^4 ∘ f^2)
    k_applyFP<<<256, 256, 0, stream>>>(y2A, y2B, Th1, Tl1, cvec1, y3A, y3B);

    // 5) sg = y3 @ dTheta (split-K pair; bias+sigmoid in leaf)
    k_thetaFP<<<512, 256, 0, stream>>>(y3A, y3B, Dh, Dl, sgA, sgB);

    // 6) leaf: sigmoid + gather product
    k_leaf2<<<B_, 256, 0, stream>>>(sgA, sgB, gvec, out);
}

// Round 12
// 98.021 us; speedup vs baseline: 1.1065x; 1.1065x over previous
//
#include <hip/hip_runtime.h>
#include <hip/hip_bf16.h>
#include <math.h>

#define B_  1024
#define S_  50
#define E_  512
#define L_  1024
#define D_  10
#define NN  1023   // N_NODES
#define LN_EPS 1e-5f
#define CBLK 72    // compose tile blocks (9 x 8 of 64x64 over 513x512)
#define DBLK 144   // W4D compose blocks (9 x 16 of 64x64 over 513x1023)

typedef short short8 __attribute__((ext_vector_type(8)));
typedef float f32x4  __attribute__((ext_vector_type(4)));
typedef unsigned short u16;
typedef unsigned int   u32;

union PackU { unsigned int u[4]; short8 s; };

// Split 8 f32 into bf16 hi (truncation; lo captures remainder exactly) and lo (RNE).
__device__ inline void split8(const float r[8], short8& hi, short8& lo) {
    PackU H, L;
#pragma unroll
    for (int q = 0; q < 4; ++q) {
        const unsigned int u0 = __float_as_uint(r[2*q+0]);
        const unsigned int u1 = __float_as_uint(r[2*q+1]);
        H.u[q] = (u0 >> 16) | (u1 & 0xFFFF0000u);
        const float h0 = __uint_as_float(u0 & 0xFFFF0000u);
        const float h1 = __uint_as_float(u1 & 0xFFFF0000u);
        const float l0 = r[2*q+0] - h0;
        const float l1 = r[2*q+1] - h1;
        unsigned int p;
        asm("v_cvt_pk_bf16_f32 %0, %1, %2" : "=v"(p) : "v"(l0), "v"(l1));
        L.u[q] = p;
    }
    hi = H.s; lo = L.s;
}

__device__ inline void split1(float v, u16& h, u16& l) {
    const unsigned int u = __float_as_uint(v);
    h = (u16)(u >> 16);
    const float hf = __uint_as_float(u & 0xFFFF0000u);
    const float lo = v - hf;
    unsigned int p;
    asm("v_cvt_pk_bf16_f32 %0, %1, %2" : "=v"(p) : "v"(lo), "v"(lo));
    l = (u16)(p & 0xFFFFu);
}

__device__ inline void split2(float v0, float v1, u32& hw, u32& lw) {
    const unsigned int u0 = __float_as_uint(v0);
    const unsigned int u1 = __float_as_uint(v1);
    hw = (u0 >> 16) | (u1 & 0xFFFF0000u);
    const float h0 = __uint_as_float(u0 & 0xFFFF0000u);
    const float h1 = __uint_as_float(u1 & 0xFFFF0000u);
    const float l0 = v0 - h0;
    const float l1 = v1 - h1;
    asm("v_cvt_pk_bf16_f32 %0, %1, %2" : "=v"(lw) : "v"(l0), "v"(l1));
}

// ---------------- bf16-plane pipelined 64x64 GEMM core (K=512) ----------------------
struct BFrag { short8 ah[2], al[2], bh[2], bl[2]; };

__device__ inline void loadB(BFrag& f,
                             const u16* pah0, const u16* pal0,
                             const u16* pah1, const u16* pal1,
                             const u16* pbh0, const u16* pbl0,
                             const u16* pbh1, const u16* pbl1, int off) {
    f.ah[0] = *reinterpret_cast<const short8*>(pah0 + off);
    f.al[0] = *reinterpret_cast<const short8*>(pal0 + off);
    f.ah[1] = *reinterpret_cast<const short8*>(pah1 + off);
    f.al[1] = *reinterpret_cast<const short8*>(pal1 + off);
    f.bh[0] = *reinterpret_cast<const short8*>(pbh0 + off);
    f.bl[0] = *reinterpret_cast<const short8*>(pbl0 + off);
    f.bh[1] = *reinterpret_cast<const short8*>(pbh1 + off);
    f.bl[1] = *reinterpret_cast<const short8*>(pbl1 + off);
}

template<int TERMS>
__device__ inline void compB(const BFrag& f, f32x4 acc[2][2]) {
#pragma unroll
    for (int i = 0; i < 2; ++i)
#pragma unroll
        for (int j = 0; j < 2; ++j) {
            acc[i][j] = __builtin_amdgcn_mfma_f32_16x16x32_bf16(f.ah[i], f.bh[j], acc[i][j], 0, 0, 0);
            acc[i][j] = __builtin_amdgcn_mfma_f32_16x16x32_bf16(f.ah[i], f.bl[j], acc[i][j], 0, 0, 0);
            acc[i][j] = __builtin_amdgcn_mfma_f32_16x16x32_bf16(f.al[i], f.bh[j], acc[i][j], 0, 0, 0);
            if (TERMS == 4)
                acc[i][j] = __builtin_amdgcn_mfma_f32_16x16x32_bf16(f.al[i], f.bl[j], acc[i][j], 0, 0, 0);
        }
}

template<int TERMS>
__device__ inline void gemmB(const u16* pah0, const u16* pal0,
                             const u16* pah1, const u16* pal1,
                             const u16* pbh0, const u16* pbl0,
                             const u16* pbh1, const u16* pbl1,
                             f32x4 acc[2][2]) {
    BFrag f0, f1;
    loadB(f0, pah0, pal0, pah1, pal1, pbh0, pbl0, pbh1, pbl1, 0);
#pragma unroll 1
    for (int kt = 0; kt < 16; kt += 2) {
        loadB(f1, pah0, pal0, pah1, pal1, pbh0, pbl0, pbh1, pbl1, (kt + 1) * 32);
        compB<TERMS>(f0, acc);
        if (kt + 2 < 16) loadB(f0, pah0, pal0, pah1, pal1, pbh0, pbl0, pbh1, pbl1, (kt + 2) * 32);
        compB<TERMS>(f1, acc);
    }
}

// ---------------- embed row: one block = one batch row, writes bf16 planes ---------
__device__ inline void do_embed_row(const int* __restrict__ ids,
                                    const float* __restrict__ emb,
                                    u16* __restrict__ xah, u16* __restrict__ xal, int b) {
    const int t = threadIdx.x;
    float a0 = 0.f, a1 = 0.f;
    const int* idr = ids + b * S_;
#pragma unroll 5
    for (int s = 0; s < S_; ++s) {
        const float2 v = *reinterpret_cast<const float2*>(emb + (long)idr[s] * E_ + 2 * t);
        a0 += v.x;
        a1 += v.y;
    }
    a0 *= (1.f / S_);
    a1 *= (1.f / S_);

    __shared__ float red[256];
    red[t] = a0 + a1;
    __syncthreads();
    for (int off = 128; off > 0; off >>= 1) {
        if (t < off) red[t] += red[t + off];
        __syncthreads();
    }
    const float mean = red[0] * (1.f / E_);
    __syncthreads();
    const float d0 = a0 - mean, d1 = a1 - mean;
    red[t] = d0 * d0 + d1 * d1;
    __syncthreads();
    for (int off = 128; off > 0; off >>= 1) {
        if (t < off) red[t] += red[t + off];
        __syncthreads();
    }
    const float var = red[0] * (1.f / E_);
    const float inv = 1.f / sqrtf(var + LN_EPS);
    u32 hw, lw;
    split2(d0 * inv, d1 * inv, hw, lw);
    *reinterpret_cast<u32*>(xah + (long)b * E_ + 2 * t) = hw;
    *reinterpret_cast<u32*>(xal + (long)b * E_ + 2 * t) = lw;
}

// ---------------- Dpack: D planes + gvec = thb[:,1]-thb[:,0] ------------------------
__device__ inline void do_dpack(const float* __restrict__ thW,
                                u16* __restrict__ Dh, u16* __restrict__ Dl,
                                const float* __restrict__ thb,
                                float* __restrict__ gvec, int part) {
    const int tid = threadIdx.x;
    const int p0 = part * 256 + tid;
    if (p0 < NN)       gvec[p0] = thb[2 * p0 + 1] - thb[2 * p0];
    else if (p0 == NN) gvec[p0] = 0.f;
    const int total = NN * 256;
    const int nth = 64 * 256;
    for (int p = p0; p < total; p += nth) {
        const int n = p >> 8;
        const int kp = p & 255;
        const float4 v = *reinterpret_cast<const float4*>(thW + (long)n * 1024 + kp * 4);
        u32 hw, lw;
        split2(v.y - v.x, v.w - v.z, hw, lw);
        *reinterpret_cast<u32*>(Dh + (long)n * E_ + kp * 2) = hw;
        *reinterpret_cast<u32*>(Dl + (long)n * E_ + kp * 2) = lw;
    }
}

// ---------------- shared compose epilogue: planes + transposed planes + cvec --------
__device__ inline void compose_epilogue(f32x4 acc[2][2], int row_base, int col_base,
                                        int kg, int r_lo,
                                        const float* __restrict__ Bbias,
                                        u16* __restrict__ Ch, u16* __restrict__ Cl,
                                        u16* __restrict__ Th, u16* __restrict__ Tl,
                                        float* __restrict__ cvec) {
#pragma unroll
    for (int j = 0; j < 2; ++j) {
        const int col = col_base + j * 16 + r_lo;
        const float bb = Bbias[col];
#pragma unroll
        for (int i = 0; i < 2; ++i) {
            const int row0 = row_base + i * 16 + kg * 4;
            union { ushort4 v; u16 e[4]; } th, tl;
#pragma unroll
            for (int r2 = 0; r2 < 4; ++r2) {
                const int row = row0 + r2;
                float v = acc[i][j][r2];
                if (row == E_) { v += bb; cvec[col] = v; }
                u16 h, l;
                split1(v, h, l);
                if (row <= E_ && Ch != nullptr) {
                    Ch[(long)row * E_ + col] = h;
                    Cl[(long)row * E_ + col] = l;
                }
                th.e[r2] = h; tl.e[r2] = l;
            }
            if (row0 + 3 < E_) {
                *reinterpret_cast<ushort4*>(Th + (long)col * E_ + row0) = th.v;
                *reinterpret_cast<ushort4*>(Tl + (long)col * E_ + row0) = tl.v;
            }
        }
    }
}

// ---------------- compose0: P2 = [Wh;bh] ∘ [Wh;bh]  (f32 inputs, 4-term) ------------
__device__ inline void do_compose0(const float* __restrict__ Wh, const float* __restrict__ bh,
                                   u16* __restrict__ Ch, u16* __restrict__ Cl,
                                   u16* __restrict__ Th, u16* __restrict__ Tl,
                                   float* __restrict__ cvec, int bid) {
    const int tid  = threadIdx.x;
    const int wid  = tid >> 6;
    const int lane = tid & 63;
    const int r_lo = lane & 15;
    const int kg   = lane >> 4;
    const int row_base = (bid >> 3) * 64 + (wid >> 1) * 32;
    const int col_base = (bid & 7) * 64 + (wid & 1) * 32;
    f32x4 acc[2][2] = {};
#pragma unroll 2
    for (int kt = 0; kt < E_; kt += 32) {
        const int ks = kt + kg * 8;
        short8 ah[2], al[2], bhf[2], blf[2];
#pragma unroll
        for (int i = 0; i < 2; ++i) {
            const int row = row_base + i * 16 + r_lo;
            const float* ap = (row < E_) ? (Wh + (long)row * E_ + ks) : (bh + ks);
            const float4 v0 = *reinterpret_cast<const float4*>(ap);
            const float4 v1 = *reinterpret_cast<const float4*>(ap + 4);
            const float rr[8] = {v0.x, v0.y, v0.z, v0.w, v1.x, v1.y, v1.z, v1.w};
            split8(rr, ah[i], al[i]);
        }
#pragma unroll
        for (int j = 0; j < 2; ++j) {
            const int c = col_base + j * 16 + r_lo;
            float rr[8];
#pragma unroll
            for (int q = 0; q < 8; ++q) rr[q] = Wh[(long)(ks + q) * E_ + c];
            split8(rr, bhf[j], blf[j]);
        }
#pragma unroll
        for (int i = 0; i < 2; ++i)
#pragma unroll
            for (int j = 0; j < 2; ++j) {
                acc[i][j] = __builtin_amdgcn_mfma_f32_16x16x32_bf16(ah[i], bhf[j], acc[i][j], 0, 0, 0);
                acc[i][j] = __builtin_amdgcn_mfma_f32_16x16x32_bf16(ah[i], blf[j], acc[i][j], 0, 0, 0);
                acc[i][j] = __builtin_amdgcn_mfma_f32_16x16x32_bf16(al[i], bhf[j], acc[i][j], 0, 0, 0);
                acc[i][j] = __builtin_amdgcn_mfma_f32_16x16x32_bf16(al[i], blf[j], acc[i][j], 0, 0, 0);
            }
    }
    compose_epilogue(acc, row_base, col_base, kg, r_lo, bh, Ch, Cl, Th, Tl, cvec);
}

// ---------------- compose (bf16 planes): C = A(513x512) ∘then B ---------------------
__device__ inline void do_composeB(const u16* __restrict__ Ah, const u16* __restrict__ Al,
                                   const u16* __restrict__ Bh, const u16* __restrict__ Bl,
                                   const float* __restrict__ Bbias,
                                   u16* __restrict__ Ch, u16* __restrict__ Cl,
                                   u16* __restrict__ Th, u16* __restrict__ Tl,
                                   float* __restrict__ cvec, int bid) {
    const int tid  = threadIdx.x;
    const int wid  = tid >> 6;
    const int lane = tid & 63;
    const int r_lo = lane & 15;
    const int kg   = lane >> 4;
    const int row_base = (bid >> 3) * 64 + (wid >> 1) * 32;
    const int col_base = (bid & 7) * 64 + (wid & 1) * 32;

    int ra0 = row_base + r_lo;        if (ra0 > E_) ra0 = E_;
    int ra1 = row_base + 16 + r_lo;   if (ra1 > E_) ra1 = E_;
    const long rb0 = col_base + r_lo;
    const long rb1 = col_base + 16 + r_lo;

    f32x4 acc[2][2] = {};
    gemmB<4>(Ah + (long)ra0 * E_ + kg * 8, Al + (long)ra0 * E_ + kg * 8,
             Ah + (long)ra1 * E_ + kg * 8, Al + (long)ra1 * E_ + kg * 8,
             Bh + rb0 * E_ + kg * 8,       Bl + rb0 * E_ + kg * 8,
             Bh + rb1 * E_ + kg * 8,       Bl + rb1 * E_ + kg * 8, acc);

    compose_epilogue(acc, row_base, col_base, kg, r_lo, Bbias, Ch, Cl, Th, Tl, cvec);
}

// ---------------- composeD: Ld = [M4;c4](513x512) @ D(512x1023) + [0;gvec] ----------
// A = Ch1/Cl1 normal planes; B = Dh/Dl (n-major k-contig). Writes transposed planes
// Lh/Ll (1023x512) and gg[col] (bias row, f32). Column-guarded at NN.
__device__ inline void do_composeD(const u16* __restrict__ Ah, const u16* __restrict__ Al,
                                   const u16* __restrict__ Dh, const u16* __restrict__ Dl,
                                   const float* __restrict__ gvec,
                                   u16* __restrict__ Lh, u16* __restrict__ Ll,
                                   float* __restrict__ gg, int bid) {
    const int tid  = threadIdx.x;
    const int wid  = tid >> 6;
    const int lane = tid & 63;
    const int r_lo = lane & 15;
    const int kg   = lane >> 4;
    const int row_base = (bid >> 4) * 64 + (wid >> 1) * 32;   // bid/16: 0..8
    const int col_base = (bid & 15) * 64 + (wid & 1) * 32;    // bid%16: 0..15

    int ra0 = row_base + r_lo;        if (ra0 > E_) ra0 = E_;
    int ra1 = row_base + 16 + r_lo;   if (ra1 > E_) ra1 = E_;
    long c0 = col_base + r_lo;        if (c0 > NN - 1) c0 = NN - 1;
    long c1 = col_base + 16 + r_lo;   if (c1 > NN - 1) c1 = NN - 1;

    f32x4 acc[2][2] = {};
    gemmB<4>(Ah + (long)ra0 * E_ + kg * 8, Al + (long)ra0 * E_ + kg * 8,
             Ah + (long)ra1 * E_ + kg * 8, Al + (long)ra1 * E_ + kg * 8,
             Dh + c0 * E_ + kg * 8,        Dl + c0 * E_ + kg * 8,
             Dh + c1 * E_ + kg * 8,        Dl + c1 * E_ + kg * 8, acc);

#pragma unroll
    for (int j = 0; j < 2; ++j) {
        const int col = col_base + j * 16 + r_lo;
        const float bb = (col < NN) ? gvec[col] : 0.f;
#pragma unroll
        for (int i = 0; i < 2; ++i) {
            const int row0 = row_base + i * 16 + kg * 4;
            union { ushort4 v; u16 e[4]; } th, tl;
#pragma unroll
            for (int r2 = 0; r2 < 4; ++r2) {
                const int row = row0 + r2;
                float v = acc[i][j][r2];
                if (row == E_) { v += bb; if (col < NN) gg[col] = v; }
                u16 h, l;
                split1(v, h, l);
                th.e[r2] = h; tl.e[r2] = l;
            }
            if (row0 + 3 < E_ && col < NN) {
                *reinterpret_cast<ushort4*>(Lh + (long)col * E_ + row0) = th.v;
                *reinterpret_cast<ushort4*>(Ll + (long)col * E_ + row0) = tl.v;
            }
        }
    }
}

// ---------------- apply (bf16 planes): Y = X(1024x512) @ M + c ----------------------
__device__ inline void do_applyB(const u16* __restrict__ Xh, const u16* __restrict__ Xl,
                                 const u16* __restrict__ Mh, const u16* __restrict__ Ml,
                                 const float* __restrict__ cvec,
                                 u16* __restrict__ Yh, u16* __restrict__ Yl,
                                 int tr, int tc) {
    const int tid  = threadIdx.x;
    const int wid  = tid >> 6;
    const int lane = tid & 63;
    const int r_lo = lane & 15;
    const int kg   = lane >> 4;
    const int row_base = tr * 64 + (wid >> 1) * 32;
    const int col_base = tc * 64 + (wid & 1) * 32;

    const long ra0 = row_base + r_lo;
    const long ra1 = row_base + 16 + r_lo;
    const long rb0 = col_base + r_lo;
    const long rb1 = col_base + 16 + r_lo;

    f32x4 acc[2][2] = {};
    gemmB<3>(Xh + ra0 * E_ + kg * 8, Xl + ra0 * E_ + kg * 8,
             Xh + ra1 * E_ + kg * 8, Xl + ra1 * E_ + kg * 8,
             Mh + rb0 * E_ + kg * 8, Ml + rb0 * E_ + kg * 8,
             Mh + rb1 * E_ + kg * 8, Ml + rb1 * E_ + kg * 8, acc);

#pragma unroll
    for (int j = 0; j < 2; ++j) {
        const int col = col_base + j * 16 + r_lo;
        const float bb = cvec[col];
#pragma unroll
        for (int i = 0; i < 2; ++i) {
#pragma unroll
            for (int r2 = 0; r2 < 4; ++r2) {
                const int row = row_base + i * 16 + kg * 4 + r2;
                u16 h, l;
                split1(acc[i][j][r2] + bb, h, l);
                Yh[(long)row * E_ + col] = h;
                Yl[(long)row * E_ + col] = l;
            }
        }
    }
}

// ---------------- fused kernels -----------------------------------------------------
// k0: P2 compose + ALL embed rows + Dpack(+gvec)
__global__ __launch_bounds__(256) void k_fused0(const float* __restrict__ Wh,
                                                const float* __restrict__ bh,
                                                u16* __restrict__ Ch0, u16* __restrict__ Cl0,
                                                u16* __restrict__ Th0, u16* __restrict__ Tl0,
                                                float* __restrict__ cvec0,
                                                const int* __restrict__ ids,
                                                const float* __restrict__ emb,
                                                u16* __restrict__ xah, u16* __restrict__ xal,
                                                const float* __restrict__ thW,
                                                u16* __restrict__ Dh, u16* __restrict__ Dl,
                                                const float* __restrict__ thb,
                                                float* __restrict__ gvec) {
    const int bid = blockIdx.x;
    if (bid < CBLK)             do_compose0(Wh, bh, Ch0, Cl0, Th0, Tl0, cvec0, bid);
    else if (bid < CBLK + 1024) do_embed_row(ids, emb, xah, xal, bid - CBLK);
    else                        do_dpack(thW, Dh, Dl, thb, gvec, bid - CBLK - 1024);
}

// k1: P4 compose (normal + T planes) + y1 = xa@M2 + c2
__global__ __launch_bounds__(256) void k_fused1(const u16* __restrict__ Ch0, const u16* __restrict__ Cl0,
                                                const u16* __restrict__ Th0, const u16* __restrict__ Tl0,
                                                const float* __restrict__ cvec0,
                                                u16* __restrict__ Ch1, u16* __restrict__ Cl1,
                                                u16* __restrict__ Th1, u16* __restrict__ Tl1,
                                                float* __restrict__ cvec1,
                                                const u16* __restrict__ xah, const u16* __restrict__ xal,
                                                u16* __restrict__ y1h, u16* __restrict__ y1l) {
    const int bid = blockIdx.x;
    if (bid < CBLK) {
        do_composeB(Ch0, Cl0, Th0, Tl0, cvec0, Ch1, Cl1, Th1, Tl1, cvec1, bid);  // P4
    } else {
        const int t = bid - CBLK;
        do_applyB(xah, xal, Th0, Tl0, cvec0, y1h, y1l, t >> 3, t & 7);           // y1 = f^2(x)
    }
}

// k2: Ld = [M4;c4]@D + [0;g]  (144 blocks)  ||  y2 = y1@M4 + c4  (128 blocks)
__global__ __launch_bounds__(256) void k_fused2(const u16* __restrict__ Ch1, const u16* __restrict__ Cl1,
                                                const u16* __restrict__ Th1, const u16* __restrict__ Tl1,
                                                const float* __restrict__ cvec1,
                                                const u16* __restrict__ Dh, const u16* __restrict__ Dl,
                                                const float* __restrict__ gvec,
                                                u16* __restrict__ Lh, u16* __restrict__ Ll,
                                                float* __restrict__ gg,
                                                const u16* __restrict__ y1h, const u16* __restrict__ y1l,
                                                u16* __restrict__ y2h, u16* __restrict__ y2l) {
    const int bid = blockIdx.x;
    if (bid < DBLK) {
        do_composeD(Ch1, Cl1, Dh, Dl, gvec, Lh, Ll, gg, bid);                    // M4@D
    } else {
        const int t = bid - DBLK;
        do_applyB(y1h, y1l, Th1, Tl1, cvec1, y2h, y2l, t >> 3, t & 7);           // y2 = f^6(x)
    }
}

// k3: sig[b][n] = sigmoid(y2 . Ld_n + gg_n)
__global__ __launch_bounds__(256) void k_theta_sig(const u16* __restrict__ Xh, const u16* __restrict__ Xl,
                                                   const u16* __restrict__ Lh, const u16* __restrict__ Ll,
                                                   const float* __restrict__ gg,
                                                   float* __restrict__ sig) {
    const int tid  = threadIdx.x;
    const int wid  = tid >> 6;
    const int lane = tid & 63;
    const int r_lo = lane & 15;
    const int kg   = lane >> 4;
    const int tr = blockIdx.x >> 4;
    const int tc = blockIdx.x & 15;
    const int row_base = tr * 64 + (wid >> 1) * 32;
    const int col_base = tc * 64 + (wid & 1) * 32;

    long c0 = col_base + r_lo;        if (c0 > NN - 1) c0 = NN - 1;
    long c1 = col_base + 16 + r_lo;   if (c1 > NN - 1) c1 = NN - 1;
    const long ra0 = row_base + r_lo;
    const long ra1 = row_base + 16 + r_lo;

    f32x4 acc[2][2] = {};
    gemmB<3>(Xh + ra0 * E_ + kg * 8, Xl + ra0 * E_ + kg * 8,
             Xh + ra1 * E_ + kg * 8, Xl + ra1 * E_ + kg * 8,
             Lh + c0 * E_ + kg * 8,  Ll + c0 * E_ + kg * 8,
             Lh + c1 * E_ + kg * 8,  Ll + c1 * E_ + kg * 8, acc);

#pragma unroll
    for (int j = 0; j < 2; ++j) {
        const int col = col_base + j * 16 + r_lo;
        const int cc = (col > NN - 1) ? (NN - 1) : col;
        const float bb = gg[cc];
#pragma unroll
        for (int i = 0; i < 2; ++i) {
#pragma unroll
            for (int r2 = 0; r2 < 4; ++r2) {
                const int row = row_base + i * 16 + kg * 4 + r2;
                if (col < NN) {
                    const float z = acc[i][j][r2] + bb;
                    sig[(long)row * 1024 + col] = 1.f / (1.f + __expf(-z));
                }
            }
        }
    }
}

// k4: leaf — per-row LDS gather of 10 sigmoids per leaf
__global__ __launch_bounds__(256) void k_leaf_gather(const float* __restrict__ sig,
                                                     float* __restrict__ out) {
    __shared__ float s[1024];
    const int b = blockIdx.x;
    const int tid = threadIdx.x;
    reinterpret_cast<float4*>(s)[tid] =
        reinterpret_cast<const float4*>(sig + (long)b * 1024)[tid];
    __syncthreads();
    float* orow = out + (long)b * L_;
#pragma unroll 1
    for (int q = 0; q < 4; ++q) {
        const int l = q * 256 + tid;
        float p = 1.f;
#pragma unroll
        for (int t = 0; t < D_; ++t) {
            const int node = (1 << t) - 1 + (l >> (D_ - t));
            const int bit  = (l >> (D_ - 1 - t)) & 1;
            const float sv = s[node];
            p *= bit ? sv : (1.f - sv);
        }
        orow[l] = p;
    }
}

extern "C" void kernel_launch(void* const* d_in, const int* in_sizes, int n_in,
                              void* d_out, int out_size, void* d_ws, size_t ws_size,
                              hipStream_t stream) {
    const int*   ids = (const int*)d_in[0];
    const float* emb = (const float*)d_in[1];
    const float* Wh  = (const float*)d_in[2];
    const float* bh  = (const float*)d_in[3];
    const float* thW = (const float*)d_in[4];
    const float* thb = (const float*)d_in[5];
    float* out = (float*)d_out;

    char* ws = (char*)d_ws;
    const size_t MB = 1u << 20;
    u16* xah = (u16*)(ws + 0 * MB);            // [1024][512] bf16 planes
    u16* xal = (u16*)(ws + 1 * MB);
    u16* y1h = (u16*)(ws + 2 * MB);
    u16* y1l = (u16*)(ws + 3 * MB);
    u16* y2h = (u16*)(ws + 4 * MB);
    u16* y2l = (u16*)(ws + 5 * MB);
    float* sig = (float*)(ws + 6 * MB);        // [1024][1024] f32 (4 MB)
    u16* Dh  = (u16*)(ws + 10 * MB);           // [1023][512]
    u16* Dl  = (u16*)(ws + 11 * MB);
    u16* Ch0 = (u16*)(ws + 12 * MB);           // [513][512] P2 normal planes
    u16* Cl0 = (u16*)(ws + 13 * MB);
    u16* Ch1 = (u16*)(ws + 14 * MB);           // [513][512] P4 normal planes
    u16* Cl1 = (u16*)(ws + 15 * MB);
    u16* Th0 = (u16*)(ws + 16 * MB);           // [512][512] transposed planes
    u16* Tl0 = (u16*)(ws + 16 * MB + 512 * 1024);
    u16* Th1 = (u16*)(ws + 17 * MB);
    u16* Tl1 = (u16*)(ws + 17 * MB + 512 * 1024);
    u16* Lh  = (u16*)(ws + 18 * MB);           // [1023][512] Ld transposed planes (~1 MB)
    u16* Ll  = (u16*)(ws + 19 * MB);
    float* cvec0 = (float*)(ws + 20 * MB);
    float* cvec1 = (float*)(ws + 20 * MB + 4096);
    float* gvec  = (float*)(ws + 20 * MB + 8192);
    float* gg    = (float*)(ws + 20 * MB + 12288);

    // 1) P2 compose + ALL embed rows + Dpack(+gvec)
    k_fused0<<<CBLK + 1024 + 64, 256, 0, stream>>>(Wh, bh, Ch0, Cl0, Th0, Tl0, cvec0,
                                                   ids, emb, xah, xal, thW, Dh, Dl,
                                                   thb, gvec);

    // 2) P4 compose + y1 = xa@M2 + c2
    k_fused1<<<CBLK + 128, 256, 0, stream>>>(Ch0, Cl0, Th0, Tl0, cvec0,
                                             Ch1, Cl1, Th1, Tl1, cvec1,
                                             xah, xal, y1h, y1l);

    // 3) Ld = [M4;c4]@D + [0;g]   ||   y2 = y1@M4 + c4
    k_fused2<<<DBLK + 128, 256, 0, stream>>>(Ch1, Cl1, Th1, Tl1, cvec1,
                                             Dh, Dl, gvec, Lh, Ll, gg,
                                             y1h, y1l, y2h, y2l);

    // 4) sig = sigmoid(y2 @ Ld + gg)
    k_theta_sig<<<256, 256, 0, stream>>>(y2h, y2l, Lh, Ll, gg, sig);

    // 5) leaf products via gather
    k_leaf_gather<<<B_, 256, 0, stream>>>(sig, out);
}